// Round 1
// baseline (657.897 us; speedup 1.0000x reference)
//
#include <hip/hip_runtime.h>
#include <hip/hip_bf16.h>

#define N_NODES 100000
#define N_EDGES 1600000
#define IN_DIM 128
#define HID 32

// ---------------- Layer-1 GEMM: h1 = x @ W1, el1 = h1@al1, er1 = h1@ar1 ----------------
// Also zero-initializes num1 and denom1 accumulators (ws is poisoned 0xAA each call).
// 8 rows per 256-thread block; thread (r, col) computes h[row][col].
__global__ __launch_bounds__(256) void gemm1_kernel(
    const float* __restrict__ x, const float* __restrict__ W,
    const float* __restrict__ al, const float* __restrict__ ar,
    float* __restrict__ h, float* __restrict__ el, float* __restrict__ er,
    float* __restrict__ num, float* __restrict__ denom)
{
    __shared__ float Ws[IN_DIM][HID];   // 16 KB
    __shared__ float Xs[8][IN_DIM];     // 4 KB
    const int tid = threadIdx.x;
    const int row0 = blockIdx.x * 8;

    // Stage W1 (4096 floats = 1024 float4)
    {
        const float4* W4 = (const float4*)W;
        float4* Ws4 = (float4*)&Ws[0][0];
        #pragma unroll
        for (int i = 0; i < 4; ++i) Ws4[tid + 256 * i] = W4[tid + 256 * i];
    }
    // Stage 8 rows of x (1024 floats = 256 float4) -- N==100000 is divisible by 8
    {
        const float4* X4 = (const float4*)(x + (size_t)row0 * IN_DIM);
        float4* Xs4 = (float4*)&Xs[0][0];
        Xs4[tid] = X4[tid];
    }
    __syncthreads();

    const int r = tid >> 5, col = tid & 31;
    const int row = row0 + r;
    float acc = 0.f;
    #pragma unroll
    for (int k = 0; k < IN_DIM; k += 4) {
        float4 xv = *(const float4*)&Xs[r][k];
        acc += xv.x * Ws[k][col] + xv.y * Ws[k + 1][col]
             + xv.z * Ws[k + 2][col] + xv.w * Ws[k + 3][col];
    }

    h[(size_t)row * HID + col] = acc;
    num[(size_t)row * HID + col] = 0.f;

    float elp = acc * al[col];
    float erp = acc * ar[col];
    #pragma unroll
    for (int m = 16; m > 0; m >>= 1) {
        elp += __shfl_xor(elp, m, 32);
        erp += __shfl_xor(erp, m, 32);
    }
    if (col == 0) {
        el[row] = elp;
        er[row] = erp;
        denom[row] = 0.f;
    }
}

// ---------------- Edge pass (both layers): num[dst] += w*h[src], denom[dst] += w -------
// w = exp(leakyrelu(el[src]+er[dst])).  Softmax max-subtraction dropped (exactly
// cancels in num/denom; logits are O(10) so f32 exp is safe).
// 32 lanes per edge (one per column), 8 edges per 256-thread block.
__global__ __launch_bounds__(256) void edge_kernel(
    const int* __restrict__ src, const int* __restrict__ dst,
    const float* __restrict__ el, const float* __restrict__ er,
    const float* __restrict__ h,
    float* __restrict__ num, float* __restrict__ denom)
{
    const int g = threadIdx.x >> 5;
    const int col = threadIdx.x & 31;
    const long e = (long)blockIdx.x * 8 + g;   // E==1.6M divisible by 8
    const int s = src[e];
    const int d = dst[e];
    float sc = el[s] + er[d];
    sc = sc > 0.f ? sc : 0.2f * sc;            // LeakyReLU(0.2)
    const float w = __expf(sc);
    const float v = w * h[(size_t)s * HID + col];
    atomicAdd(&num[(size_t)d * HID + col], v);
    if (col == 0) atomicAdd(&denom[d], w);
}

// ---------------- Layer-2 GEMM with fused layer-1 epilogue -----------------------------
// x2 = elu(num1/denom1 + b1); h2 = x2 @ W2; el2/er2; zero num2 (= d_out) and denom2.
__global__ __launch_bounds__(256) void gemm2_kernel(
    const float* __restrict__ num1, const float* __restrict__ dn1,
    const float* __restrict__ b1, const float* __restrict__ W,
    const float* __restrict__ al, const float* __restrict__ ar,
    float* __restrict__ h, float* __restrict__ el, float* __restrict__ er,
    float* __restrict__ num2, float* __restrict__ dn2)
{
    __shared__ float Ws[HID][HID];  // 4 KB
    __shared__ float Xs[8][HID];    // 1 KB
    const int tid = threadIdx.x;
    const int row0 = blockIdx.x * 8;
    const int r = tid >> 5, c = tid & 31;
    const int row = row0 + r;

    // Stage W2 (1024 floats = 256 float4)
    ((float4*)&Ws[0][0])[tid] = ((const float4*)W)[tid];

    // Stage activations with fused epilogue: /denom, +b1, ELU
    {
        const float den = dn1[row];
        float v = num1[(size_t)row * HID + c];
        v = den > 0.f ? v / den : 0.f;
        v += b1[c];
        v = v > 0.f ? v : expm1f(v);  // ELU alpha=1
        Xs[r][c] = v;
    }
    __syncthreads();

    float acc = 0.f;
    #pragma unroll
    for (int k = 0; k < HID; ++k) acc += Xs[r][k] * Ws[k][c];

    h[(size_t)row * HID + c] = acc;
    num2[(size_t)row * HID + c] = 0.f;

    float elp = acc * al[c];
    float erp = acc * ar[c];
    #pragma unroll
    for (int m = 16; m > 0; m >>= 1) {
        elp += __shfl_xor(elp, m, 32);
        erp += __shfl_xor(erp, m, 32);
    }
    if (c == 0) {
        el[row] = elp;
        er[row] = erp;
        dn2[row] = 0.f;
    }
}

// ---------------- Final epilogue: out = num2/denom2 + b2 -------------------------------
__global__ __launch_bounds__(256) void final_kernel(
    const float* __restrict__ dn2, const float* __restrict__ b2,
    float* __restrict__ out)
{
    const int i = blockIdx.x * 256 + threadIdx.x;   // N*32 divisible by 256
    const int row = i >> 5, c = i & 31;
    const float den = dn2[row];
    float v = out[i];
    v = den > 0.f ? v / den : 0.f;
    out[i] = v + b2[c];
}

extern "C" void kernel_launch(void* const* d_in, const int* in_sizes, int n_in,
                              void* d_out, int out_size, void* d_ws, size_t ws_size,
                              hipStream_t stream) {
    const float* features = (const float*)d_in[0];
    const int*   src      = (const int*)d_in[1];
    const int*   dst      = (const int*)d_in[2];
    const float* W1       = (const float*)d_in[3];
    const float* al1      = (const float*)d_in[4];
    const float* ar1      = (const float*)d_in[5];
    const float* b1       = (const float*)d_in[6];
    const float* W2       = (const float*)d_in[7];
    const float* al2      = (const float*)d_in[8];
    const float* ar2      = (const float*)d_in[9];
    const float* b2       = (const float*)d_in[10];
    float* out = (float*)d_out;

    // Workspace layout (floats): h1[N*32] el1[N] er1[N] dn1[N] num1[N*32]
    //                            h2[N*32] el2[N] er2[N] dn2[N]        (~40 MB)
    float* ws  = (float*)d_ws;
    float* h1   = ws;
    float* el1  = h1  + (size_t)N_NODES * HID;
    float* er1  = el1 + N_NODES;
    float* dn1  = er1 + N_NODES;
    float* num1 = dn1 + N_NODES;
    float* h2   = num1 + (size_t)N_NODES * HID;
    float* el2  = h2  + (size_t)N_NODES * HID;
    float* er2  = el2 + N_NODES;
    float* dn2  = er2 + N_NODES;

    // Layer 1
    gemm1_kernel<<<N_NODES / 8, 256, 0, stream>>>(features, W1, al1, ar1,
                                                  h1, el1, er1, num1, dn1);
    edge_kernel<<<N_EDGES / 8, 256, 0, stream>>>(src, dst, el1, er1, h1, num1, dn1);
    // Layer 2 (fused ELU epilogue of layer 1); num2 accumulates directly in d_out
    gemm2_kernel<<<N_NODES / 8, 256, 0, stream>>>(num1, dn1, b1, W2, al2, ar2,
                                                  h2, el2, er2, out, dn2);
    edge_kernel<<<N_EDGES / 8, 256, 0, stream>>>(src, dst, el2, er2, h2, out, dn2);
    final_kernel<<<(N_NODES * HID) / 256, 256, 0, stream>>>(dn2, b2, out);
}

// Round 2
// 535.797 us; speedup vs baseline: 1.2279x; 1.2279x over previous
//
#include <hip/hip_runtime.h>
#include <hip/hip_bf16.h>

#define N_NODES 100000
#define N_EDGES 1600000
#define IN_DIM 128
#define HID 32

// ======================= Layer-1 GEMM: h1 = x@W1, el1, er1 ============================
// Also zeroes deg[] (ws is poisoned 0xAA each call) for the CSR histogram that follows.
__global__ __launch_bounds__(256) void gemm1_kernel(
    const float* __restrict__ x, const float* __restrict__ W,
    const float* __restrict__ al, const float* __restrict__ ar,
    float* __restrict__ h, float* __restrict__ el, float* __restrict__ er,
    int* __restrict__ deg)
{
    __shared__ float Ws[IN_DIM][HID];   // 16 KB
    __shared__ float Xs[8][IN_DIM];     // 4 KB
    const int tid = threadIdx.x;
    const int row0 = blockIdx.x * 8;

    // zero deg[] using the first 100000 global threads
    const int gid = blockIdx.x * 256 + tid;
    if (gid < N_NODES) deg[gid] = 0;

    {   // stage W1 (4096 floats)
        const float4* W4 = (const float4*)W;
        float4* Ws4 = (float4*)&Ws[0][0];
        #pragma unroll
        for (int i = 0; i < 4; ++i) Ws4[tid + 256 * i] = W4[tid + 256 * i];
    }
    {   // stage 8 rows of x
        const float4* X4 = (const float4*)(x + (size_t)row0 * IN_DIM);
        ((float4*)&Xs[0][0])[tid] = X4[tid];
    }
    __syncthreads();

    const int r = tid >> 5, col = tid & 31;
    const int row = row0 + r;
    float acc = 0.f;
    #pragma unroll
    for (int k = 0; k < IN_DIM; k += 4) {
        float4 xv = *(const float4*)&Xs[r][k];
        acc += xv.x * Ws[k][col] + xv.y * Ws[k + 1][col]
             + xv.z * Ws[k + 2][col] + xv.w * Ws[k + 3][col];
    }
    h[(size_t)row * HID + col] = acc;

    float elp = acc * al[col];
    float erp = acc * ar[col];
    #pragma unroll
    for (int m = 16; m > 0; m >>= 1) {
        elp += __shfl_xor(elp, m, 32);
        erp += __shfl_xor(erp, m, 32);
    }
    if (col == 0) { el[row] = elp; er[row] = erp; }
}

// ======================= CSR build ====================================================
__global__ __launch_bounds__(256) void hist_kernel(const int* __restrict__ dst,
                                                   int* __restrict__ deg)
{
    const int e = blockIdx.x * 256 + threadIdx.x;   // grid covers E exactly
    atomicAdd(&deg[dst[e]], 1);
}

// Per-block (1024-elem) exclusive scan of deg -> rowptr, block totals -> bsum
__global__ __launch_bounds__(256) void scanA_kernel(const int* __restrict__ deg,
                                                    int* __restrict__ rowptr,
                                                    int* __restrict__ bsum)
{
    const int t = threadIdx.x;
    const int base = blockIdx.x * 1024 + t * 4;
    int v0 = (base + 0 < N_NODES) ? deg[base + 0] : 0;
    int v1 = (base + 1 < N_NODES) ? deg[base + 1] : 0;
    int v2 = (base + 2 < N_NODES) ? deg[base + 2] : 0;
    int v3 = (base + 3 < N_NODES) ? deg[base + 3] : 0;
    const int s = v0 + v1 + v2 + v3;
    const int lane = t & 63, wid = t >> 6;
    int pre = s;
    #pragma unroll
    for (int off = 1; off < 64; off <<= 1) {
        int n = __shfl_up(pre, off, 64);
        if (lane >= off) pre += n;
    }
    __shared__ int wsums[4];
    if (lane == 63) wsums[wid] = pre;
    __syncthreads();
    int wo = 0;
    for (int k = 0; k < wid; ++k) wo += wsums[k];
    int run = wo + pre - s;   // exclusive prefix for this thread's 4 elems
    if (base + 0 < N_NODES) rowptr[base + 0] = run; run += v0;
    if (base + 1 < N_NODES) rowptr[base + 1] = run; run += v1;
    if (base + 2 < N_NODES) rowptr[base + 2] = run; run += v2;
    if (base + 3 < N_NODES) rowptr[base + 3] = run;
    if (t == 255) bsum[blockIdx.x] = wo + pre;   // block total
}

// Exclusive scan of the 98 block sums (single block, 128 threads)
__global__ __launch_bounds__(128) void scanB_kernel(int* __restrict__ bsum, int nb)
{
    const int t = threadIdx.x;
    int v = (t < nb) ? bsum[t] : 0;
    const int lane = t & 63, wid = t >> 6;
    int pre = v;
    #pragma unroll
    for (int off = 1; off < 64; off <<= 1) {
        int n = __shfl_up(pre, off, 64);
        if (lane >= off) pre += n;
    }
    __shared__ int ws2[2];
    if (lane == 63) ws2[wid] = pre;
    __syncthreads();
    if (wid == 1) pre += ws2[0];
    if (t < nb) bsum[t] = pre - v;   // exclusive
}

// Add block offsets; init write cursors
__global__ __launch_bounds__(256) void scanC_kernel(int* __restrict__ rowptr,
                                                    const int* __restrict__ bsum,
                                                    int* __restrict__ wptr)
{
    const int i = blockIdx.x * 256 + threadIdx.x;
    if (i < N_NODES) {
        int r = rowptr[i] + bsum[i >> 10];
        rowptr[i] = r;
        wptr[i] = r;
    }
}

__global__ __launch_bounds__(256) void scatter_kernel(const int* __restrict__ src,
                                                      const int* __restrict__ dst,
                                                      int* __restrict__ wptr,
                                                      int* __restrict__ csr_src)
{
    const int e = blockIdx.x * 256 + threadIdx.x;
    const int slot = atomicAdd(&wptr[dst[e]], 1);
    csr_src[slot] = src[e];
}

// ======================= Gather-aggregate (both layers) ===============================
// One wave64 per dst node: lanes = (e2, col), e2 = lane>>5 strides the edge list,
// col = lane&31 is the feature column. num/den accumulate in registers; epilogue fused.
// MODE 0: out = elu(num/den + b)  (layer-1 -> x2)    MODE 1: out = num/den + b (final)
template <int MODE>
__global__ __launch_bounds__(256) void gather_kernel(
    const int* __restrict__ rowptr, const int* __restrict__ deg,
    const int* __restrict__ csr_src,
    const float* __restrict__ el, const float* __restrict__ er,
    const float* __restrict__ h, const float* __restrict__ bias,
    float* __restrict__ out)
{
    const int tid = threadIdx.x;
    const int node = blockIdx.x * 4 + (tid >> 6);    // grid = N/4 exactly
    const int e2 = (tid >> 5) & 1, col = tid & 31;
    const int start = rowptr[node];
    const int cnt = deg[node];
    const float erd = er[node];
    float acc = 0.f, den = 0.f;
    for (int j = e2; j < cnt; j += 2) {
        const int s = csr_src[start + j];
        float sc = el[s] + erd;
        sc = sc > 0.f ? sc : 0.2f * sc;              // LeakyReLU(0.2)
        const float w = __expf(sc);
        den += w;
        acc += w * h[(size_t)s * HID + col];
    }
    acc += __shfl_xor(acc, 32, 64);
    den += __shfl_xor(den, 32, 64);
    if (e2 == 0) {
        float v = den > 0.f ? acc / den : 0.f;
        v += bias[col];
        if (MODE == 0) v = v > 0.f ? v : expm1f(v);  // ELU
        out[(size_t)node * HID + col] = v;
    }
}

// ======================= Layer-2 GEMM: h2 = x2@W2, el2, er2 ===========================
__global__ __launch_bounds__(256) void gemm2_kernel(
    const float* __restrict__ x2, const float* __restrict__ W,
    const float* __restrict__ al, const float* __restrict__ ar,
    float* __restrict__ h, float* __restrict__ el, float* __restrict__ er)
{
    __shared__ float Ws[HID][HID];  // 4 KB
    __shared__ float Xs[8][HID];    // 1 KB
    const int tid = threadIdx.x;
    const int row0 = blockIdx.x * 8;
    const int r = tid >> 5, c = tid & 31;
    const int row = row0 + r;

    ((float4*)&Ws[0][0])[tid] = ((const float4*)W)[tid];
    Xs[r][c] = x2[(size_t)row * HID + c];
    __syncthreads();

    float acc = 0.f;
    #pragma unroll
    for (int k = 0; k < HID; ++k) acc += Xs[r][k] * Ws[k][c];
    h[(size_t)row * HID + c] = acc;

    float elp = acc * al[c];
    float erp = acc * ar[c];
    #pragma unroll
    for (int m = 16; m > 0; m >>= 1) {
        elp += __shfl_xor(elp, m, 32);
        erp += __shfl_xor(erp, m, 32);
    }
    if (c == 0) { el[row] = elp; er[row] = erp; }
}

extern "C" void kernel_launch(void* const* d_in, const int* in_sizes, int n_in,
                              void* d_out, int out_size, void* d_ws, size_t ws_size,
                              hipStream_t stream) {
    const float* features = (const float*)d_in[0];
    const int*   src      = (const int*)d_in[1];
    const int*   dst      = (const int*)d_in[2];
    const float* W1       = (const float*)d_in[3];
    const float* al1      = (const float*)d_in[4];
    const float* ar1      = (const float*)d_in[5];
    const float* b1       = (const float*)d_in[6];
    const float* W2       = (const float*)d_in[7];
    const float* al2      = (const float*)d_in[8];
    const float* ar2      = (const float*)d_in[9];
    const float* b2       = (const float*)d_in[10];
    float* out = (float*)d_out;

    // Workspace layout
    int* deg     = (int*)d_ws;
    int* rowptr  = deg + N_NODES;
    int* wptr    = rowptr + N_NODES;
    int* bsum    = wptr + N_NODES;           // 128 ints
    int* csr_src = bsum + 128;
    float* fbase = (float*)(csr_src + N_EDGES);
    float* h1  = fbase;
    float* el1 = h1 + (size_t)N_NODES * HID;
    float* er1 = el1 + N_NODES;
    float* x2  = er1 + N_NODES;
    float* h2  = x2 + (size_t)N_NODES * HID;
    float* el2 = h2 + (size_t)N_NODES * HID;
    float* er2 = el2 + N_NODES;

    const int NB_SCAN = (N_NODES + 1023) / 1024;   // 98

    // Layer-1 GEMM (+ zero deg)
    gemm1_kernel<<<N_NODES / 8, 256, 0, stream>>>(features, W1, al1, ar1,
                                                  h1, el1, er1, deg);
    // CSR build
    hist_kernel<<<N_EDGES / 256, 256, 0, stream>>>(dst, deg);
    scanA_kernel<<<NB_SCAN, 256, 0, stream>>>(deg, rowptr, bsum);
    scanB_kernel<<<1, 128, 0, stream>>>(bsum, NB_SCAN);
    scanC_kernel<<<(N_NODES + 255) / 256, 256, 0, stream>>>(rowptr, bsum, wptr);
    scatter_kernel<<<N_EDGES / 256, 256, 0, stream>>>(src, dst, wptr, csr_src);
    // Layer-1 aggregate -> x2 = elu(num/den + b1)
    gather_kernel<0><<<N_NODES / 4, 256, 0, stream>>>(rowptr, deg, csr_src,
                                                      el1, er1, h1, b1, x2);
    // Layer-2 GEMM
    gemm2_kernel<<<N_NODES / 8, 256, 0, stream>>>(x2, W2, al2, ar2, h2, el2, er2);
    // Layer-2 aggregate -> out = num/den + b2
    gather_kernel<1><<<N_NODES / 4, 256, 0, stream>>>(rowptr, deg, csr_src,
                                                      el2, er2, h2, b2, out);
}

// Round 3
// 473.640 us; speedup vs baseline: 1.3890x; 1.1312x over previous
//
#include <hip/hip_runtime.h>
#include <hip/hip_bf16.h>

#define N_NODES 100000
#define N_EDGES 1600000
#define IN_DIM 128
#define HID 32

// ======================= Layer-1 GEMM: h1 = x@W1, el1, er1 ============================
// Also zeroes deg[] (ws is poisoned 0xAA each call) for the CSR histogram that follows.
__global__ __launch_bounds__(256) void gemm1_kernel(
    const float* __restrict__ x, const float* __restrict__ W,
    const float* __restrict__ al, const float* __restrict__ ar,
    float* __restrict__ h, float* __restrict__ el, float* __restrict__ er,
    int* __restrict__ deg)
{
    __shared__ float Ws[IN_DIM][HID];   // 16 KB
    __shared__ float Xs[8][IN_DIM];     // 4 KB
    const int tid = threadIdx.x;
    const int row0 = blockIdx.x * 8;

    // zero deg[] using the first 100000 global threads
    const int gid = blockIdx.x * 256 + tid;
    if (gid < N_NODES) deg[gid] = 0;

    {   // stage W1 (4096 floats)
        const float4* W4 = (const float4*)W;
        float4* Ws4 = (float4*)&Ws[0][0];
        #pragma unroll
        for (int i = 0; i < 4; ++i) Ws4[tid + 256 * i] = W4[tid + 256 * i];
    }
    {   // stage 8 rows of x
        const float4* X4 = (const float4*)(x + (size_t)row0 * IN_DIM);
        ((float4*)&Xs[0][0])[tid] = X4[tid];
    }
    __syncthreads();

    const int r = tid >> 5, col = tid & 31;
    const int row = row0 + r;
    float acc = 0.f;
    #pragma unroll
    for (int k = 0; k < IN_DIM; k += 4) {
        float4 xv = *(const float4*)&Xs[r][k];
        acc += xv.x * Ws[k][col] + xv.y * Ws[k + 1][col]
             + xv.z * Ws[k + 2][col] + xv.w * Ws[k + 3][col];
    }
    h[(size_t)row * HID + col] = acc;

    float elp = acc * al[col];
    float erp = acc * ar[col];
    #pragma unroll
    for (int m = 16; m > 0; m >>= 1) {
        elp += __shfl_xor(elp, m, 32);
        erp += __shfl_xor(erp, m, 32);
    }
    if (col == 0) { el[row] = elp; er[row] = erp; }
}

// ======================= CSR build ====================================================
// 8 edges/thread for memory-level parallelism (atomics are memory-side, ~600cy).
__global__ __launch_bounds__(256) void hist_kernel(const int* __restrict__ dst,
                                                   int* __restrict__ deg)
{
    const int t = blockIdx.x * 256 + threadIdx.x;
    if (t >= N_EDGES / 8) return;
    const int4* d4 = (const int4*)dst;
    const int4 a = d4[2 * t], b = d4[2 * t + 1];
    atomicAdd(&deg[a.x], 1); atomicAdd(&deg[a.y], 1);
    atomicAdd(&deg[a.z], 1); atomicAdd(&deg[a.w], 1);
    atomicAdd(&deg[b.x], 1); atomicAdd(&deg[b.y], 1);
    atomicAdd(&deg[b.z], 1); atomicAdd(&deg[b.w], 1);
}

// Per-block (1024-elem) exclusive scan of deg -> rowptr, block totals -> bsum
__global__ __launch_bounds__(256) void scanA_kernel(const int* __restrict__ deg,
                                                    int* __restrict__ rowptr,
                                                    int* __restrict__ bsum)
{
    const int t = threadIdx.x;
    const int base = blockIdx.x * 1024 + t * 4;
    int v0 = (base + 0 < N_NODES) ? deg[base + 0] : 0;
    int v1 = (base + 1 < N_NODES) ? deg[base + 1] : 0;
    int v2 = (base + 2 < N_NODES) ? deg[base + 2] : 0;
    int v3 = (base + 3 < N_NODES) ? deg[base + 3] : 0;
    const int s = v0 + v1 + v2 + v3;
    const int lane = t & 63, wid = t >> 6;
    int pre = s;
    #pragma unroll
    for (int off = 1; off < 64; off <<= 1) {
        int n = __shfl_up(pre, off, 64);
        if (lane >= off) pre += n;
    }
    __shared__ int wsums[4];
    if (lane == 63) wsums[wid] = pre;
    __syncthreads();
    int wo = 0;
    for (int k = 0; k < wid; ++k) wo += wsums[k];
    int run = wo + pre - s;   // exclusive prefix for this thread's 4 elems
    if (base + 0 < N_NODES) rowptr[base + 0] = run; run += v0;
    if (base + 1 < N_NODES) rowptr[base + 1] = run; run += v1;
    if (base + 2 < N_NODES) rowptr[base + 2] = run; run += v2;
    if (base + 3 < N_NODES) rowptr[base + 3] = run;
    if (t == 255) bsum[blockIdx.x] = wo + pre;   // block total
}

// Exclusive scan of the 98 block sums (single block, 128 threads)
__global__ __launch_bounds__(128) void scanB_kernel(int* __restrict__ bsum, int nb)
{
    const int t = threadIdx.x;
    int v = (t < nb) ? bsum[t] : 0;
    const int lane = t & 63, wid = t >> 6;
    int pre = v;
    #pragma unroll
    for (int off = 1; off < 64; off <<= 1) {
        int n = __shfl_up(pre, off, 64);
        if (lane >= off) pre += n;
    }
    __shared__ int ws2[2];
    if (lane == 63) ws2[wid] = pre;
    __syncthreads();
    if (wid == 1) pre += ws2[0];
    if (t < nb) bsum[t] = pre - v;   // exclusive
}

// Add block offsets to rowptr (rowptr doubles as the scatter cursor; after the
// scatter it holds each segment's END, and gather recomputes start = end - deg).
__global__ __launch_bounds__(256) void scanC_kernel(int* __restrict__ rowptr,
                                                    const int* __restrict__ bsum)
{
    const int i = blockIdx.x * 256 + threadIdx.x;
    if (i < N_NODES) rowptr[i] += bsum[i >> 10];
}

// 8 edges/thread: 8 independent atomic-rtns in flight hides the ~600cy memory-side
// atomic latency that made the 1-edge/thread version latency-bound (12 G atomics/s).
__global__ __launch_bounds__(256) void scatter_kernel(const int* __restrict__ src,
                                                      const int* __restrict__ dst,
                                                      int* __restrict__ cursor,
                                                      int* __restrict__ csr_src)
{
    const int t = blockIdx.x * 256 + threadIdx.x;
    if (t >= N_EDGES / 8) return;
    const int4* s4 = (const int4*)src;
    const int4* d4 = (const int4*)dst;
    const int4 sa = s4[2 * t], sb = s4[2 * t + 1];
    const int4 da = d4[2 * t], db = d4[2 * t + 1];
    const int p0 = atomicAdd(&cursor[da.x], 1);
    const int p1 = atomicAdd(&cursor[da.y], 1);
    const int p2 = atomicAdd(&cursor[da.z], 1);
    const int p3 = atomicAdd(&cursor[da.w], 1);
    const int p4 = atomicAdd(&cursor[db.x], 1);
    const int p5 = atomicAdd(&cursor[db.y], 1);
    const int p6 = atomicAdd(&cursor[db.z], 1);
    const int p7 = atomicAdd(&cursor[db.w], 1);
    csr_src[p0] = sa.x; csr_src[p1] = sa.y;
    csr_src[p2] = sa.z; csr_src[p3] = sa.w;
    csr_src[p4] = sb.x; csr_src[p5] = sb.y;
    csr_src[p6] = sb.z; csr_src[p7] = sb.w;
}

// ======================= Gather-aggregate (both layers) ===============================
// One wave64 per dst node: lanes = (e2, col); 2x-unrolled edge loop for MLP on the
// csr->el/h dependent chains. rowptr[node] holds segment END (post-scatter).
// MODE 0: out = elu(num/den + b)  (layer-1 -> x2)    MODE 1: out = num/den + b (final)
template <int MODE>
__global__ __launch_bounds__(256) void gather_kernel(
    const int* __restrict__ rowptr, const int* __restrict__ deg,
    const int* __restrict__ csr_src,
    const float* __restrict__ el, const float* __restrict__ er,
    const float* __restrict__ h, const float* __restrict__ bias,
    float* __restrict__ out)
{
    const int tid = threadIdx.x;
    const int node = blockIdx.x * 4 + (tid >> 6);    // grid = N/4 exactly
    const int e2 = (tid >> 5) & 1, col = tid & 31;
    const int cnt = deg[node];
    const int start = rowptr[node] - cnt;
    const float erd = er[node];
    float acc = 0.f, den = 0.f;
    int j = e2;
    for (; j + 2 < cnt; j += 4) {
        const int sA = csr_src[start + j];
        const int sB = csr_src[start + j + 2];
        float scA = el[sA] + erd;
        float scB = el[sB] + erd;
        const float hA = h[(size_t)sA * HID + col];
        const float hB = h[(size_t)sB * HID + col];
        scA = scA > 0.f ? scA : 0.2f * scA;
        scB = scB > 0.f ? scB : 0.2f * scB;
        const float wA = __expf(scA);
        const float wB = __expf(scB);
        den += wA + wB;
        acc += wA * hA + wB * hB;
    }
    if (j < cnt) {
        const int s = csr_src[start + j];
        float sc = el[s] + erd;
        sc = sc > 0.f ? sc : 0.2f * sc;
        const float w = __expf(sc);
        den += w;
        acc += w * h[(size_t)s * HID + col];
    }
    acc += __shfl_xor(acc, 32, 64);
    den += __shfl_xor(den, 32, 64);
    if (e2 == 0) {
        float v = den > 0.f ? acc / den : 0.f;
        v += bias[col];
        if (MODE == 0) v = v > 0.f ? v : expm1f(v);  // ELU
        out[(size_t)node * HID + col] = v;
    }
}

// ======================= Layer-2 GEMM: h2 = x2@W2, el2, er2 ===========================
__global__ __launch_bounds__(256) void gemm2_kernel(
    const float* __restrict__ x2, const float* __restrict__ W,
    const float* __restrict__ al, const float* __restrict__ ar,
    float* __restrict__ h, float* __restrict__ el, float* __restrict__ er)
{
    __shared__ float Ws[HID][HID];  // 4 KB
    __shared__ float Xs[8][HID];    // 1 KB
    const int tid = threadIdx.x;
    const int row0 = blockIdx.x * 8;
    const int r = tid >> 5, c = tid & 31;
    const int row = row0 + r;

    ((float4*)&Ws[0][0])[tid] = ((const float4*)W)[tid];
    Xs[r][c] = x2[(size_t)row * HID + c];
    __syncthreads();

    float acc = 0.f;
    #pragma unroll
    for (int k = 0; k < HID; ++k) acc += Xs[r][k] * Ws[k][c];
    h[(size_t)row * HID + c] = acc;

    float elp = acc * al[c];
    float erp = acc * ar[c];
    #pragma unroll
    for (int m = 16; m > 0; m >>= 1) {
        elp += __shfl_xor(elp, m, 32);
        erp += __shfl_xor(erp, m, 32);
    }
    if (c == 0) { el[row] = elp; er[row] = erp; }
}

extern "C" void kernel_launch(void* const* d_in, const int* in_sizes, int n_in,
                              void* d_out, int out_size, void* d_ws, size_t ws_size,
                              hipStream_t stream) {
    const float* features = (const float*)d_in[0];
    const int*   src      = (const int*)d_in[1];
    const int*   dst      = (const int*)d_in[2];
    const float* W1       = (const float*)d_in[3];
    const float* al1      = (const float*)d_in[4];
    const float* ar1      = (const float*)d_in[5];
    const float* b1       = (const float*)d_in[6];
    const float* W2       = (const float*)d_in[7];
    const float* al2      = (const float*)d_in[8];
    const float* ar2      = (const float*)d_in[9];
    const float* b2       = (const float*)d_in[10];
    float* out = (float*)d_out;

    // Workspace layout
    int* deg     = (int*)d_ws;
    int* rowptr  = deg + N_NODES;
    int* bsum    = rowptr + N_NODES;         // 128 ints
    int* csr_src = bsum + 128;
    float* fbase = (float*)(csr_src + N_EDGES);
    float* h1  = fbase;
    float* el1 = h1 + (size_t)N_NODES * HID;
    float* er1 = el1 + N_NODES;
    float* x2  = er1 + N_NODES;
    float* h2  = x2 + (size_t)N_NODES * HID;
    float* el2 = h2 + (size_t)N_NODES * HID;
    float* er2 = el2 + N_NODES;

    const int NB_SCAN = (N_NODES + 1023) / 1024;           // 98
    const int NB_E8   = (N_EDGES / 8 + 255) / 256;         // 782

    // Layer-1 GEMM (+ zero deg)
    gemm1_kernel<<<N_NODES / 8, 256, 0, stream>>>(features, W1, al1, ar1,
                                                  h1, el1, er1, deg);
    // CSR build
    hist_kernel<<<NB_E8, 256, 0, stream>>>(dst, deg);
    scanA_kernel<<<NB_SCAN, 256, 0, stream>>>(deg, rowptr, bsum);
    scanB_kernel<<<1, 128, 0, stream>>>(bsum, NB_SCAN);
    scanC_kernel<<<(N_NODES + 255) / 256, 256, 0, stream>>>(rowptr, bsum);
    scatter_kernel<<<NB_E8, 256, 0, stream>>>(src, dst, rowptr, csr_src);
    // Layer-1 aggregate -> x2 = elu(num/den + b1)
    gather_kernel<0><<<N_NODES / 4, 256, 0, stream>>>(rowptr, deg, csr_src,
                                                      el1, er1, h1, b1, x2);
    // Layer-2 GEMM
    gemm2_kernel<<<N_NODES / 8, 256, 0, stream>>>(x2, W2, al2, ar2, h2, el2, er2);
    // Layer-2 aggregate -> out = num/den + b2
    gather_kernel<1><<<N_NODES / 4, 256, 0, stream>>>(rowptr, deg, csr_src,
                                                      el2, er2, h2, b2, out);
}